// Round 17
// baseline (174.665 us; speedup 1.0000x reference)
//
#include <hip/hip_runtime.h>
#include <stdint.h>
#include <math.h>

typedef unsigned int u32;
typedef unsigned long long u64;

#define NBUCKET 16384   // radix = top 14 bits of order-preserving key
#define BSHIFT  18      // u >> 18 -> 14-bit bucket
#define HBINS 16512     // LDS histogram bins in k_finish (>= P+2)
#define SMAX 2560       // LDS floats per A/B quarter-window in k_main
#define NSPLIT 4        // j-split factor

__device__ __forceinline__ u32 f2key(float f){
  u32 b = __float_as_uint(f);
  return (b & 0x80000000u) ? ~b : (b | 0x80000000u);
}

// ---- 1024-thread (16-wave) primitives (proven R12) ----
__device__ __forceinline__ double blk_reduce_d(double v, int tid, double* ds){
  int lane = tid & 63, wid = tid >> 6;
  for (int off=32; off>0; off>>=1) v += __shfl_down(v, off);
  if (lane==0) ds[wid] = v;
  __syncthreads();
  if (tid < 64){
    double t = (tid<16)? ds[tid] : 0.0;
    for (int off=8; off>0; off>>=1) t += __shfl_down(t, off);
    if (tid==0) ds[16] = t;
  }
  __syncthreads();
  double r = ds[16];
  __syncthreads();
  return r;
}

// inclusive scan; after return ds[15] == block total (caller barriers before reuse)
__device__ __forceinline__ double blk_scan_incl_d(double v, int tid, double* ds){
  int lane = tid & 63, wid = tid >> 6;
  double sv = v;
  for (int off=1; off<64; off<<=1){
    double o = __shfl_up(sv, off);
    if (lane >= off) sv += o;
  }
  if (lane==63) ds[wid] = sv;
  __syncthreads();
  if (tid < 64){
    double w = (tid<16)? ds[tid] : 0.0;
    for (int off=1; off<16; off<<=1){
      double o = __shfl_up(w, off);
      if (tid >= off) w += o;
    }
    if (tid<16) ds[tid] = w;
  }
  __syncthreads();
  double add = (wid>0)? ds[wid-1] : 0.0;
  return sv + add;
}

__device__ __forceinline__ u32 blk_scan_incl_u32(u32 v, int tid, u32* ws){
  int lane = tid & 63, wid = tid >> 6;
  u32 sv = v;
  for (int off=1; off<64; off<<=1){
    u32 o = __shfl_up(sv, off);
    if (lane >= off) sv += o;
  }
  if (lane==63) ws[wid] = sv;
  __syncthreads();
  if (tid < 64){
    u32 w = (tid<16)? ws[tid] : 0u;
    for (int off=1; off<16; off<<=1){
      u32 o = __shfl_up(w, off);
      if (tid >= off) w += o;
    }
    if (tid<16) ws[tid] = w;
  }
  __syncthreads();
  u32 add = (wid>0)? ws[wid-1] : 0u;
  return sv + add;
}

// Fused: bucket histogram + D-table fill (no Pcnt atomic; P derived in k_scan).
__global__ void k_hist(const float* __restrict__ scores, const int* __restrict__ labels,
                       int B, int NC, u32* __restrict__ bhist,
                       float* __restrict__ Dsh, int SD){
  int t = blockIdx.x*256 + threadIdx.x;
  if (t < 4*SD){
    int p = t / SD, y = t - p*SD;
    long long x = (long long)y + p;
    Dsh[t] = (x==0) ? 0.0f : (float)(1.0/log2(1.0 + (double)x));
  }
  if (t >= B*NC) return;
  int b = t / NC, c = t - (t/NC)*NC;
  float v = scores[t];
  int isPos = (labels[b] == c);
  u32 u = f2key(v);
  u32 bucket = u >> BSHIFT;
  int pi = c*2 + (isPos ? 0 : 1);   // part0=pos, part1=neg
  atomicAdd(&bhist[(size_t)pi*NBUCKET + bucket], 1u);
}

// Exclusive scan of 16384 bins per (class,part); also derives Pcnt (pi even).
__global__ void k_scan(const u32* __restrict__ bhist, u32* __restrict__ bstart,
                       u32* __restrict__ bcursor, u32* __restrict__ Pcnt){
  __shared__ u32 ws[17];
  int pi = blockIdx.x, tid = threadIdx.x;
  const u32* h = bhist + (size_t)pi*NBUCKET;
  u32 v[16]; u32 tot = 0u;
  #pragma unroll
  for (int k=0;k<16;k++){ v[k] = h[tid*16+k]; tot += v[k]; }
  u32 incl = blk_scan_incl_u32(tot, tid, ws);
  u32 run = incl - tot;  // exclusive prefix for this thread's 16 bins
  u32* bs = bstart  + (size_t)pi*(NBUCKET+1);
  u32* bc = bcursor + (size_t)pi*NBUCKET;
  #pragma unroll
  for (int k=0;k<16;k++){ bs[tid*16+k]=run; bc[tid*16+k]=run; run+=v[k]; }
  if (tid==1023){
    bs[NBUCKET]=incl;
    if ((pi & 1) == 0) Pcnt[pi >> 1] = incl;   // P = count of positives
  }
}

// Scatter packed keys (key<<32 | orig_index) into bucket-grouped order.
__global__ void k_scatter(const float* __restrict__ scores, const int* __restrict__ labels,
                          int B, int NC, u32* __restrict__ bcursor, u64* __restrict__ keyArr){
  int t = blockIdx.x*256 + threadIdx.x;
  if (t >= B*NC) return;
  int b = t / NC, c = t - (t/NC)*NC;
  float v = scores[t];
  int isPos = (labels[b] == c);
  u32 u = f2key(v);
  u32 bucket = u >> BSHIFT;
  int pi = c*2 + (isPos ? 0 : 1);
  u32 slot = atomicAdd(&bcursor[(size_t)pi*NBUCKET + bucket], 1u);
  keyArr[(size_t)pi*B + slot] = ((u64)u << 32) | (u32)b;
}

// Exact rank within bucket (deterministic via unique packed keys) -> sorted arrays.
__global__ void k_rank(const u64* __restrict__ keyArr, const u32* __restrict__ bstart,
                       const u32* __restrict__ Pcnt, int B,
                       float* __restrict__ sPos, float* __restrict__ sNeg){
  int pi = blockIdx.y; int c = pi >> 1; int part = pi & 1;
  u32 P = Pcnt[c];
  u32 cnt = part ? ((u32)B - P) : P;
  u32 t = blockIdx.x*256 + threadIdx.x;
  if (t >= cnt) return;
  const u64* ka = keyArr + (size_t)pi*B;
  u64 K = ka[t];
  u32 bucket = (u32)(K >> (32 + BSHIFT));
  const u32* bs = bstart + (size_t)pi*(NBUCKET+1);
  u32 lo = bs[bucket], hi = bs[bucket+1];
  u32 r = lo;
  for (u32 x=lo; x<hi; ++x) r += (ka[x] < K) ? 1u : 0u;
  u32 u = (u32)(K >> 32);
  u32 bits = (u & 0x80000000u) ? (u & 0x7fffffffu) : ~u;
  float val = __uint_as_float(bits);
  if (part == 0) sPos[(size_t)c*B + (P-1u-r)] = val;   // descending
  else           sNeg[(size_t)c*B + r]        = val;   // ascending
}

// Per-class: Cconst, shfl-scan-based suffix sums -> scaled coefficients A', B'.
__global__ void k_pre(const float* __restrict__ sPos, const u32* __restrict__ Pcnt,
                      const float* __restrict__ Dsh, int B, int strideAB,
                      float* __restrict__ Aarr, float* __restrict__ Barr,
                      double* __restrict__ Cconst){
  __shared__ double ds[17];
  int c = blockIdx.x, tid = threadIdx.x;
  u32 P = Pcnt[c]; u32 N = (u32)B - P;
  if (P==0 || N==0){ if (tid==0) Cconst[c]=1.0; return; }

  double s=0.0;
  for (u32 i=1+tid; i<=P; i+=1024) s += (double)Dsh[i];   // copy 0 == plain Dtab
  double Cc = blk_reduce_d(s, tid, ds);
  if (tid==0) Cconst[c]=Cc;

  const float* sp = sPos + (size_t)c*B;
  double ts=0.0;
  for (u32 i=tid; i<P; i+=1024) ts += (double)sp[i];
  double totSp = blk_reduce_d(ts, tid, ds);

  double PN = (double)P*(double)N;
  double ca = -2.0*Cc/PN;
  double cb =  2.0*Cc/PN;
  float* A  = Aarr + (size_t)c*strideAB;
  float* Bc = Barr + (size_t)c*strideAB;

  double carry=0.0;
  int nch = ((int)P + 1023)/1024;
  for (int ch=0; ch<nch; ++ch){
    int x = ch*1024 + tid;
    double v = (x < (int)P) ? (double)sp[x] : 0.0;
    double incl = blk_scan_incl_d(v, tid, ds);
    if (x < (int)P){
      double excl = incl - v + carry;         // sum sp[0..x-1]
      double Sl = totSp - excl;               // sum_{k=x}^{P-1} sp[k]
      A[x]  = (float)(ca*Sl);
      Bc[x] = (float)(cb*(double)(P-(u32)x));
    }
    carry += ds[15];                          // block total of this chunk
    __syncthreads();                          // protect ds for next chunk
  }
  if (tid==0){ A[P]=0.0f; Bc[P]=0.0f; }
}

// 4-way j-split brute-force argmax: blockIdx.y = c*4 + quarter.
// Inner loop uses a group-of-4 max tree (14 VALU/group vs 20); the winning
// group is resolved ONCE at the end (sA/sB persist) by recomputing its 4 f's
// with bit-identical ops -> exact leftmost-argmax. Scalar tail sets bgrp=-2.
__global__ void k_main(const float* __restrict__ sNeg, const u32* __restrict__ Pcnt,
                       const float* __restrict__ Dsh, int SD,
                       const float* __restrict__ Aarr, const float* __restrict__ Barr,
                       int B, int strideAB, u64* __restrict__ partKey){
  __shared__ __align__(16) float sA[SMAX];
  __shared__ __align__(16) float sB[SMAX];
  int cy = blockIdx.y;
  int c = cy >> 2, quarter = cy & 3;
  u32 P = Pcnt[c]; u32 N = (u32)B - P;
  int w    = threadIdx.x >> 6;
  int lane = threadIdx.x & 63;
  int m = blockIdx.x*256 + w + 4*lane;       // R9 stride-4 mapping
  const float* A  = Aarr + (size_t)c*strideAB;
  const float* Bc = Barr + (size_t)c*strideAB;
  bool classValid = (P>0u && N>0u);
  int total = (int)P + 1;
  int qLen = ((total + 4*NSPLIT - 1) / (4*NSPLIT)) * 4;  // multiple of 4
  int j0 = quarter * qLen;
  int j1 = min(total, j0 + qLen);
  int len = j1 - j0;                         // <=0 => empty quarter
  bool useLds = classValid && (len > 0) && (len <= SMAX - 4);
  if (useLds){
    const float4* A4 = (const float4*)(A + j0);   // j0 % 4 == 0, base 16B-aligned
    const float4* B4 = (const float4*)(Bc + j0);
    float4* sA4 = (float4*)sA;
    float4* sB4 = (float4*)sB;
    int nv = (len + 3) >> 2;
    for (int i = threadIdx.x; i < nv; i += 256){ sA4[i] = A4[i]; sB4[i] = B4[i]; }
  }
  __syncthreads();

  if (classValid && m < (int)N){
    if (len <= 0){
      partKey[(size_t)cy*B + m] = 0ull;      // neutral: loses the max
      return;
    }
    float sm = sNeg[(size_t)c*B + m];
    int ph = (m+1) & 3;                               // wave-uniform (m stride 4)
    const float* Dp = Dsh + (size_t)ph*SD + (m+1-ph); // 16B-aligned at j%4==0
    float best = -3.402823466e38f; u32 bj = (u32)j0;
    int bgrp = -1;                             // pending winning group (abs j)
    if (useLds){
      int lenv = len & ~3;
      int i = 0;
      #pragma unroll 2
      for (; i < lenv; i += 4){
        float4 d = *(const float4*)(Dp + j0 + i);
        float4 a = *(const float4*)(sA + i);
        float4 b = *(const float4*)(sB + i);
        float f0 = fmaf(b.x, sm, a.x) + d.x;
        float f1 = fmaf(b.y, sm, a.y) + d.y;
        float f2 = fmaf(b.z, sm, a.z) + d.z;
        float f3 = fmaf(b.w, sm, a.w) + d.w;
        float g = fmaxf(fmaxf(f0,f1), fmaxf(f2,f3));
        if (g > best){ best = g; bgrp = j0 + i; }    // first max group wins
      }
      for (; i < len; ++i){
        float f = fmaf(sB[i], sm, sA[i]) + Dp[j0+i];
        if (f > best){ best=f; bj=(u32)(j0+i); bgrp = -2; }
      }
      if (bgrp >= 0){
        int i2 = bgrp - j0;
        float4 a = *(const float4*)(sA + i2);
        float4 b = *(const float4*)(sB + i2);
        float4 d = *(const float4*)(Dp + bgrp);
        float f0 = fmaf(b.x, sm, a.x) + d.x;
        float f1 = fmaf(b.y, sm, a.y) + d.y;
        float f2 = fmaf(b.z, sm, a.z) + d.z;
        u32 o = (f0==best) ? 0u : (f1==best) ? 1u : (f2==best) ? 2u : 3u;
        bj = (u32)bgrp + o;
      }
    } else {
      int jv = j0 + (len & ~3);
      int j = j0;
      #pragma unroll 2
      for (; j < jv; j += 4){
        float4 d = *(const float4*)(Dp + j);
        float4 a = *(const float4*)(A + j);
        float4 b = *(const float4*)(Bc + j);
        float f0 = fmaf(b.x, sm, a.x) + d.x;
        float f1 = fmaf(b.y, sm, a.y) + d.y;
        float f2 = fmaf(b.z, sm, a.z) + d.z;
        float f3 = fmaf(b.w, sm, a.w) + d.w;
        float g = fmaxf(fmaxf(f0,f1), fmaxf(f2,f3));
        if (g > best){ best = g; bgrp = j; }
      }
      for (; j < j1; ++j){
        float f = fmaf(Bc[j], sm, A[j]) + Dp[j];
        if (f > best){ best=f; bj=(u32)j; bgrp = -2; }
      }
      if (bgrp >= 0){
        float4 a = *(const float4*)(A + bgrp);
        float4 b = *(const float4*)(Bc + bgrp);
        float4 d = *(const float4*)(Dp + bgrp);
        float f0 = fmaf(b.x, sm, a.x) + d.x;
        float f1 = fmaf(b.y, sm, a.y) + d.y;
        float f2 = fmaf(b.z, sm, a.z) + d.z;
        u32 o = (f0==best) ? 0u : (f1==best) ? 1u : (f2==best) ? 2u : 3u;
        bj = (u32)bgrp + o;
      }
    }
    partKey[(size_t)cy*B + m] = ((u64)f2key(best + 0.0f) << 32) | (u32)(~bj);
  }
}

// Per-class finish: inline combine of the four quarter-keys -> opt; LDS
// histogram + shfl chunked scan for r_plus; S1/S2 here; last block writes out.
__global__ void k_finish(const float* __restrict__ sPos, const float* __restrict__ sNeg,
                         const u32* __restrict__ Pcnt,
                         const u64* __restrict__ partKey, const float* __restrict__ Dsh,
                         const double* __restrict__ Cconst,
                         int B, int NC,
                         u64* __restrict__ classLoss, u32* __restrict__ doneCount,
                         float* __restrict__ out){
  __shared__ u32 hbins[HBINS];
  __shared__ u32 ws[17];
  __shared__ double ds[17];
  int c = blockIdx.x, tid = threadIdx.x;
  u32 P = Pcnt[c]; u32 N = (u32)B - P;
  double myLoss = 0.0;
  if (P!=0 && N!=0){
    const u64* pk0 = partKey + (size_t)(c*4+0)*B;
    const u64* pk1 = partKey + (size_t)(c*4+1)*B;
    const u64* pk2 = partKey + (size_t)(c*4+2)*B;
    const u64* pk3 = partKey + (size_t)(c*4+3)*B;
    const float* sp = sPos + (size_t)c*B;
    const float* sn = sNeg + (size_t)c*B;
    double sumD=0.0, sumSpr=0.0, sumSp=0.0, S1=0.0, S2=0.0;
    if ((int)P + 2 <= HBINS){
      for (int i = tid; i < (int)P + 2; i += 1024) hbins[i] = 0u;
      __syncthreads();
      for (int m2 = tid; m2 < (int)N; m2 += 1024){
        u64 k0 = pk0[m2], k1 = pk1[m2], k2 = pk2[m2], k3 = pk3[m2];
        u64 ka = (k0 > k1) ? k0 : k1;
        u64 kb = (k2 > k3) ? k2 : k3;
        u64 kk = (ka > kb) ? ka : kb;          // max f; tie -> smaller j (~bj)
        u32 opt = (~(u32)kk) + 1u;
        atomicAdd(&hbins[opt], 1u);            // LDS atomic
        double smv = (double)sn[m2];
        S1 += smv;
        S2 += smv * (double)opt;
      }
      __syncthreads();
      u32 carry=0u;
      int nch = ((int)P + 1023)/1024;
      for (int ch=0; ch<nch; ++ch){
        int x = ch*1024 + tid;
        u32 v = (x < (int)P) ? hbins[x+1] : 0u;
        u32 incl = blk_scan_incl_u32(v, tid, ws);
        u32 cum = incl + carry;
        if (x < (int)P){
          u32 r = 1u + cum;
          float spv = sp[x];
          sumD   += (double)Dsh[x + r];
          sumSpr += (double)spv * (double)r;
          sumSp  += (double)spv;
        }
        carry += ws[15];                       // chunk total
        __syncthreads();
      }
    } else {
      // generic exact fallback (never at B=16384)
      for (int m2 = tid; m2 < (int)N; m2 += 1024){
        u64 k0 = pk0[m2], k1 = pk1[m2], k2 = pk2[m2], k3 = pk3[m2];
        u64 ka = (k0 > k1) ? k0 : k1;
        u64 kb = (k2 > k3) ? k2 : k3;
        u64 kk = (ka > kb) ? ka : kb;
        u32 opt = (~(u32)kk) + 1u;
        double smv = (double)sn[m2];
        S1 += smv; S2 += smv * (double)opt;
      }
      for (int x = tid; x < (int)P; x += 1024){
        u32 target = (u32)x + 1u, cnt2 = 0u;
        for (u32 m2 = 0; m2 < N; ++m2){
          u64 k0 = pk0[m2], k1 = pk1[m2], k2 = pk2[m2], k3 = pk3[m2];
          u64 ka = (k0 > k1) ? k0 : k1;
          u64 kb = (k2 > k3) ? k2 : k3;
          u64 kk = (ka > kb) ? ka : kb;
          u32 opt = (~(u32)kk) + 1u;
          cnt2 += (opt <= target) ? 1u : 0u;
        }
        u32 r = 1u + cnt2;
        float spv = sp[x];
        sumD   += (double)Dsh[x + r];
        sumSpr += (double)spv * (double)r;
        sumSp  += (double)spv;
      }
    }
    double totD   = blk_reduce_d(sumD,   tid, ds);
    double totSpr = blk_reduce_d(sumSpr, tid, ds);
    double totSp  = blk_reduce_d(sumSp,  tid, ds);
    double S1t    = blk_reduce_d(S1,     tid, ds);
    double S2t    = blk_reduce_d(S2,     tid, ds);
    if (tid==0){
      double Cc = Cconst[c];
      double Delta = 1.0 - totD/Cc;
      double Fp    = (double)(N+2u)*totSp - 2.0*totSpr;   // sum s_plus*c_plus
      double Fm    = (double)(P+2u)*S1t  - 2.0*S2t;       // sum s_minus*c_minus
      double Fstar = (double)N*totSp - (double)P*S1t;
      myLoss = Delta + (Fp + Fm - Fstar)/((double)P*(double)N);
    }
  }
  if (tid==0){
    atomicExch(&classLoss[c], (u64)__double_as_longlong(myLoss));
    __threadfence();
    u32 old = atomicAdd(doneCount, 1u);
    if (old == (u32)gridDim.x - 1u){
      __threadfence();
      double s=0.0;
      for (int cc=0; cc<NC; ++cc){
        u64 bits = atomicAdd(&classLoss[cc], 0ull);  // coherent read
        s += __longlong_as_double((long long)bits);
      }
      out[0] = (float)(s/(double)NC);
    }
  }
}

extern "C" void kernel_launch(void* const* d_in, const int* in_sizes, int n_in,
                              void* d_out, int out_size, void* d_ws, size_t ws_size,
                              hipStream_t stream) {
  const float* scores = (const float*)d_in[0];
  const int*   labels = (const int*)d_in[1];
  int B  = in_sizes[1];
  int NC = in_sizes[0] / in_sizes[1];
  float* out = (float*)d_out;

  int SD = B + 8;            // per-copy stride of shifted D tables
  int strideAB = B + 8;      // per-class stride of A/B
  int nblkM = (B + 255)/256; // k_main blocks per (class, quarter)

  char* ws = (char*)d_ws;
  size_t off = 0;
  auto alloc = [&](size_t bytes)->char* {
    char* p = ws + off;
    off = (off + bytes + 255) & ~(size_t)255;
    return p;
  };
  float* Dsh = (float*)alloc((size_t)4*SD*4);
  // ---- zeroed region (must stay contiguous) ----
  char* zbeg = ws + off;
  u32* bhist     = (u32*)alloc((size_t)NC*2*NBUCKET*4);
  u32* doneCount = (u32*)alloc(4);
  char* zend = ws + off;
  // ----------------------------------------------
  u32* Pcnt      = (u32*)alloc((size_t)NC*4);       // written by k_scan
  u32* bstart    = (u32*)alloc((size_t)NC*2*(NBUCKET+1)*4);
  u32* bcursor   = (u32*)alloc((size_t)NC*2*NBUCKET*4);
  u64* keyArr    = (u64*)alloc((size_t)NC*2*B*8);
  float* sPos    = (float*)alloc((size_t)NC*B*4);
  float* sNeg    = (float*)alloc((size_t)NC*B*4);
  float* Aarr    = (float*)alloc((size_t)NC*strideAB*4);
  float* Barr    = (float*)alloc((size_t)NC*strideAB*4);
  double* Cconst = (double*)alloc((size_t)NC*8);
  u64* partKey   = (u64*)alloc((size_t)NC*NSPLIT*B*8);
  u64* classLoss = (u64*)alloc((size_t)NC*8);

  hipMemsetAsync(zbeg, 0, (size_t)(zend - zbeg), stream);

  k_hist<<<(B*NC+255)/256, 256, 0, stream>>>(scores, labels, B, NC, bhist, Dsh, SD);
  k_scan<<<NC*2, 1024, 0, stream>>>(bhist, bstart, bcursor, Pcnt);
  k_scatter<<<(B*NC+255)/256, 256, 0, stream>>>(scores, labels, B, NC, bcursor, keyArr);
  k_rank<<<dim3((B+255)/256, NC*2), 256, 0, stream>>>(keyArr, bstart, Pcnt, B, sPos, sNeg);
  k_pre<<<NC, 1024, 0, stream>>>(sPos, Pcnt, Dsh, B, strideAB, Aarr, Barr, Cconst);
  k_main<<<dim3(nblkM, NC*NSPLIT), 256, 0, stream>>>(sNeg, Pcnt, Dsh, SD, Aarr, Barr,
                                                     B, strideAB, partKey);
  k_finish<<<NC, 1024, 0, stream>>>(sPos, sNeg, Pcnt, partKey, Dsh, Cconst, B, NC,
                                    classLoss, doneCount, out);
}

// Round 18
// 161.974 us; speedup vs baseline: 1.0784x; 1.0784x over previous
//
#include <hip/hip_runtime.h>
#include <stdint.h>
#include <math.h>

typedef unsigned int u32;
typedef unsigned long long u64;

#define NBUCKET 16384   // radix = top 14 bits of order-preserving key
#define BSHIFT  18      // u >> 18 -> 14-bit bucket
#define HBINS 16512     // LDS histogram bins in k_finish (>= P+2)
#define SMAX 2560       // LDS floats per A/B half-window in k_main

__device__ __forceinline__ u32 f2key(float f){
  u32 b = __float_as_uint(f);
  return (b & 0x80000000u) ? ~b : (b | 0x80000000u);
}

// ---- 1024-thread (16-wave) primitives (proven R12) ----
__device__ __forceinline__ double blk_reduce_d(double v, int tid, double* ds){
  int lane = tid & 63, wid = tid >> 6;
  for (int off=32; off>0; off>>=1) v += __shfl_down(v, off);
  if (lane==0) ds[wid] = v;
  __syncthreads();
  if (tid < 64){
    double t = (tid<16)? ds[tid] : 0.0;
    for (int off=8; off>0; off>>=1) t += __shfl_down(t, off);
    if (tid==0) ds[16] = t;
  }
  __syncthreads();
  double r = ds[16];
  __syncthreads();
  return r;
}

// inclusive scan; after return ds[15] == block total (caller barriers before reuse)
__device__ __forceinline__ double blk_scan_incl_d(double v, int tid, double* ds){
  int lane = tid & 63, wid = tid >> 6;
  double sv = v;
  for (int off=1; off<64; off<<=1){
    double o = __shfl_up(sv, off);
    if (lane >= off) sv += o;
  }
  if (lane==63) ds[wid] = sv;
  __syncthreads();
  if (tid < 64){
    double w = (tid<16)? ds[tid] : 0.0;
    for (int off=1; off<16; off<<=1){
      double o = __shfl_up(w, off);
      if (tid >= off) w += o;
    }
    if (tid<16) ds[tid] = w;
  }
  __syncthreads();
  double add = (wid>0)? ds[wid-1] : 0.0;
  return sv + add;
}

__device__ __forceinline__ u32 blk_scan_incl_u32(u32 v, int tid, u32* ws){
  int lane = tid & 63, wid = tid >> 6;
  u32 sv = v;
  for (int off=1; off<64; off<<=1){
    u32 o = __shfl_up(sv, off);
    if (lane >= off) sv += o;
  }
  if (lane==63) ws[wid] = sv;
  __syncthreads();
  if (tid < 64){
    u32 w = (tid<16)? ws[tid] : 0u;
    for (int off=1; off<16; off<<=1){
      u32 o = __shfl_up(w, off);
      if (tid >= off) w += o;
    }
    if (tid<16) ws[tid] = w;
  }
  __syncthreads();
  u32 add = (wid>0)? ws[wid-1] : 0u;
  return sv + add;
}

// Fused: bucket histogram + D-table fill (no Pcnt atomic; P derived in k_scan).
__global__ void k_hist(const float* __restrict__ scores, const int* __restrict__ labels,
                       int B, int NC, u32* __restrict__ bhist,
                       float* __restrict__ Dsh, int SD){
  int t = blockIdx.x*256 + threadIdx.x;
  if (t < 4*SD){
    int p = t / SD, y = t - p*SD;
    long long x = (long long)y + p;
    Dsh[t] = (x==0) ? 0.0f : (float)(1.0/log2(1.0 + (double)x));
  }
  if (t >= B*NC) return;
  int b = t / NC, c = t - (t/NC)*NC;
  float v = scores[t];
  int isPos = (labels[b] == c);
  u32 u = f2key(v);
  u32 bucket = u >> BSHIFT;
  int pi = c*2 + (isPos ? 0 : 1);   // part0=pos, part1=neg
  atomicAdd(&bhist[(size_t)pi*NBUCKET + bucket], 1u);
}

// Exclusive scan of 16384 bins per (class,part); also derives Pcnt (pi even).
__global__ void k_scan(const u32* __restrict__ bhist, u32* __restrict__ bstart,
                       u32* __restrict__ bcursor, u32* __restrict__ Pcnt){
  __shared__ u32 ws[17];
  int pi = blockIdx.x, tid = threadIdx.x;
  const u32* h = bhist + (size_t)pi*NBUCKET;
  u32 v[16]; u32 tot = 0u;
  #pragma unroll
  for (int k=0;k<16;k++){ v[k] = h[tid*16+k]; tot += v[k]; }
  u32 incl = blk_scan_incl_u32(tot, tid, ws);
  u32 run = incl - tot;  // exclusive prefix for this thread's 16 bins
  u32* bs = bstart  + (size_t)pi*(NBUCKET+1);
  u32* bc = bcursor + (size_t)pi*NBUCKET;
  #pragma unroll
  for (int k=0;k<16;k++){ bs[tid*16+k]=run; bc[tid*16+k]=run; run+=v[k]; }
  if (tid==1023){
    bs[NBUCKET]=incl;
    if ((pi & 1) == 0) Pcnt[pi >> 1] = incl;   // P = count of positives
  }
}

// Scatter packed keys (key<<32 | orig_index) into bucket-grouped order.
__global__ void k_scatter(const float* __restrict__ scores, const int* __restrict__ labels,
                          int B, int NC, u32* __restrict__ bcursor, u64* __restrict__ keyArr){
  int t = blockIdx.x*256 + threadIdx.x;
  if (t >= B*NC) return;
  int b = t / NC, c = t - (t/NC)*NC;
  float v = scores[t];
  int isPos = (labels[b] == c);
  u32 u = f2key(v);
  u32 bucket = u >> BSHIFT;
  int pi = c*2 + (isPos ? 0 : 1);
  u32 slot = atomicAdd(&bcursor[(size_t)pi*NBUCKET + bucket], 1u);
  keyArr[(size_t)pi*B + slot] = ((u64)u << 32) | (u32)b;
}

// Exact rank within bucket (deterministic via unique packed keys) -> sorted arrays.
__global__ void k_rank(const u64* __restrict__ keyArr, const u32* __restrict__ bstart,
                       const u32* __restrict__ Pcnt, int B,
                       float* __restrict__ sPos, float* __restrict__ sNeg){
  int pi = blockIdx.y; int c = pi >> 1; int part = pi & 1;
  u32 P = Pcnt[c];
  u32 cnt = part ? ((u32)B - P) : P;
  u32 t = blockIdx.x*256 + threadIdx.x;
  if (t >= cnt) return;
  const u64* ka = keyArr + (size_t)pi*B;
  u64 K = ka[t];
  u32 bucket = (u32)(K >> (32 + BSHIFT));
  const u32* bs = bstart + (size_t)pi*(NBUCKET+1);
  u32 lo = bs[bucket], hi = bs[bucket+1];
  u32 r = lo;
  for (u32 x=lo; x<hi; ++x) r += (ka[x] < K) ? 1u : 0u;
  u32 u = (u32)(K >> 32);
  u32 bits = (u & 0x80000000u) ? (u & 0x7fffffffu) : ~u;
  float val = __uint_as_float(bits);
  if (part == 0) sPos[(size_t)c*B + (P-1u-r)] = val;   // descending
  else           sNeg[(size_t)c*B + r]        = val;   // ascending
}

// Per-class: Cconst, shfl-scan-based suffix sums -> scaled coefficients A', B'.
__global__ void k_pre(const float* __restrict__ sPos, const u32* __restrict__ Pcnt,
                      const float* __restrict__ Dsh, int B, int strideAB,
                      float* __restrict__ Aarr, float* __restrict__ Barr,
                      double* __restrict__ Cconst){
  __shared__ double ds[17];
  int c = blockIdx.x, tid = threadIdx.x;
  u32 P = Pcnt[c]; u32 N = (u32)B - P;
  if (P==0 || N==0){ if (tid==0) Cconst[c]=1.0; return; }

  double s=0.0;
  for (u32 i=1+tid; i<=P; i+=1024) s += (double)Dsh[i];   // copy 0 == plain Dtab
  double Cc = blk_reduce_d(s, tid, ds);
  if (tid==0) Cconst[c]=Cc;

  const float* sp = sPos + (size_t)c*B;
  double ts=0.0;
  for (u32 i=tid; i<P; i+=1024) ts += (double)sp[i];
  double totSp = blk_reduce_d(ts, tid, ds);

  double PN = (double)P*(double)N;
  double ca = -2.0*Cc/PN;
  double cb =  2.0*Cc/PN;
  float* A  = Aarr + (size_t)c*strideAB;
  float* Bc = Barr + (size_t)c*strideAB;

  double carry=0.0;
  int nch = ((int)P + 1023)/1024;
  for (int ch=0; ch<nch; ++ch){
    int x = ch*1024 + tid;
    double v = (x < (int)P) ? (double)sp[x] : 0.0;
    double incl = blk_scan_incl_d(v, tid, ds);
    if (x < (int)P){
      double excl = incl - v + carry;         // sum sp[0..x-1]
      double Sl = totSp - excl;               // sum_{k=x}^{P-1} sp[k]
      A[x]  = (float)(ca*Sl);
      Bc[x] = (float)(cb*(double)(P-(u32)x));
    }
    carry += ds[15];                          // block total of this chunk
    __syncthreads();                          // protect ds for next chunk
  }
  if (tid==0){ A[P]=0.0f; Bc[P]=0.0f; }
}

// 2-way j-split brute-force argmax (R16-proven structure); ONLY change vs R16:
// group-of-4 max tree in the inner loop (14 VALU/group vs 20), with the
// winning group resolved ONCE at the end (sA/sB persist) by recomputing its
// 4 f's with bit-identical ops -> exact leftmost-argmax. Tail sets bgrp=-2.
__global__ void k_main(const float* __restrict__ sNeg, const u32* __restrict__ Pcnt,
                       const float* __restrict__ Dsh, int SD,
                       const float* __restrict__ Aarr, const float* __restrict__ Barr,
                       int B, int strideAB, u64* __restrict__ partKey){
  __shared__ __align__(16) float sA[SMAX];
  __shared__ __align__(16) float sB[SMAX];
  int cy = blockIdx.y;
  int c = cy >> 1, half = cy & 1;
  u32 P = Pcnt[c]; u32 N = (u32)B - P;
  int w    = threadIdx.x >> 6;
  int lane = threadIdx.x & 63;
  int m = blockIdx.x*256 + w + 4*lane;       // R9 stride-4 mapping
  const float* A  = Aarr + (size_t)c*strideAB;
  const float* Bc = Barr + (size_t)c*strideAB;
  bool classValid = (P>0u && N>0u);
  int total = (int)P + 1;
  int halfLen = ((total + 7) >> 3) << 2;     // multiple of 4, ~total/2
  int j0 = half * halfLen;
  int j1 = min(total, j0 + halfLen);
  int len = j1 - j0;                         // <=0 => empty half
  bool useLds = classValid && (len > 0) && (len <= SMAX - 4);
  if (useLds){
    const float4* A4 = (const float4*)(A + j0);   // j0 % 4 == 0, base 16B-aligned
    const float4* B4 = (const float4*)(Bc + j0);
    float4* sA4 = (float4*)sA;
    float4* sB4 = (float4*)sB;
    int nv = (len + 3) >> 2;
    for (int i = threadIdx.x; i < nv; i += 256){ sA4[i] = A4[i]; sB4[i] = B4[i]; }
  }
  __syncthreads();

  if (classValid && m < (int)N){
    if (len <= 0){
      partKey[(size_t)cy*B + m] = 0ull;      // neutral: loses the max
      return;
    }
    float sm = sNeg[(size_t)c*B + m];
    int ph = (m+1) & 3;                               // wave-uniform (m stride 4)
    const float* Dp = Dsh + (size_t)ph*SD + (m+1-ph); // 16B-aligned at j%4==0
    float best = -3.402823466e38f; u32 bj = (u32)j0;
    int bgrp = -1;                             // pending winning group (abs j)
    if (useLds){
      int lenv = len & ~3;
      int i = 0;
      #pragma unroll 2
      for (; i < lenv; i += 4){
        float4 d = *(const float4*)(Dp + j0 + i);
        float4 a = *(const float4*)(sA + i);
        float4 b = *(const float4*)(sB + i);
        float f0 = fmaf(b.x, sm, a.x) + d.x;
        float f1 = fmaf(b.y, sm, a.y) + d.y;
        float f2 = fmaf(b.z, sm, a.z) + d.z;
        float f3 = fmaf(b.w, sm, a.w) + d.w;
        float g = fmaxf(fmaxf(f0,f1), fmaxf(f2,f3));
        if (g > best){ best = g; bgrp = j0 + i; }    // first max group wins
      }
      for (; i < len; ++i){
        float f = fmaf(sB[i], sm, sA[i]) + Dp[j0+i];
        if (f > best){ best=f; bj=(u32)(j0+i); bgrp = -2; }
      }
      if (bgrp >= 0){
        int i2 = bgrp - j0;
        float4 a = *(const float4*)(sA + i2);
        float4 b = *(const float4*)(sB + i2);
        float4 d = *(const float4*)(Dp + bgrp);
        float f0 = fmaf(b.x, sm, a.x) + d.x;
        float f1 = fmaf(b.y, sm, a.y) + d.y;
        float f2 = fmaf(b.z, sm, a.z) + d.z;
        u32 o = (f0==best) ? 0u : (f1==best) ? 1u : (f2==best) ? 2u : 3u;
        bj = (u32)bgrp + o;
      }
    } else {
      int jv = j0 + (len & ~3);
      int j = j0;
      #pragma unroll 2
      for (; j < jv; j += 4){
        float4 d = *(const float4*)(Dp + j);
        float4 a = *(const float4*)(A + j);
        float4 b = *(const float4*)(Bc + j);
        float f0 = fmaf(b.x, sm, a.x) + d.x;
        float f1 = fmaf(b.y, sm, a.y) + d.y;
        float f2 = fmaf(b.z, sm, a.z) + d.z;
        float f3 = fmaf(b.w, sm, a.w) + d.w;
        float g = fmaxf(fmaxf(f0,f1), fmaxf(f2,f3));
        if (g > best){ best = g; bgrp = j; }
      }
      for (; j < j1; ++j){
        float f = fmaf(Bc[j], sm, A[j]) + Dp[j];
        if (f > best){ best=f; bj=(u32)j; bgrp = -2; }
      }
      if (bgrp >= 0){
        float4 a = *(const float4*)(A + bgrp);
        float4 b = *(const float4*)(Bc + bgrp);
        float4 d = *(const float4*)(Dp + bgrp);
        float f0 = fmaf(b.x, sm, a.x) + d.x;
        float f1 = fmaf(b.y, sm, a.y) + d.y;
        float f2 = fmaf(b.z, sm, a.z) + d.z;
        u32 o = (f0==best) ? 0u : (f1==best) ? 1u : (f2==best) ? 2u : 3u;
        bj = (u32)bgrp + o;
      }
    }
    partKey[(size_t)cy*B + m] = ((u64)f2key(best + 0.0f) << 32) | (u32)(~bj);
  }
}

// Per-class finish: inline combine of the two half-keys -> opt; LDS histogram
// + shfl chunked scan for r_plus; S1/S2 computed here; last block writes out.
__global__ void k_finish(const float* __restrict__ sPos, const float* __restrict__ sNeg,
                         const u32* __restrict__ Pcnt,
                         const u64* __restrict__ partKey, const float* __restrict__ Dsh,
                         const double* __restrict__ Cconst,
                         int B, int NC,
                         u64* __restrict__ classLoss, u32* __restrict__ doneCount,
                         float* __restrict__ out){
  __shared__ u32 hbins[HBINS];
  __shared__ u32 ws[17];
  __shared__ double ds[17];
  int c = blockIdx.x, tid = threadIdx.x;
  u32 P = Pcnt[c]; u32 N = (u32)B - P;
  double myLoss = 0.0;
  if (P!=0 && N!=0){
    const u64* pk0 = partKey + (size_t)(c*2+0)*B;
    const u64* pk1 = partKey + (size_t)(c*2+1)*B;
    const float* sp = sPos + (size_t)c*B;
    const float* sn = sNeg + (size_t)c*B;
    double sumD=0.0, sumSpr=0.0, sumSp=0.0, S1=0.0, S2=0.0;
    if ((int)P + 2 <= HBINS){
      for (int i = tid; i < (int)P + 2; i += 1024) hbins[i] = 0u;
      __syncthreads();
      for (int m2 = tid; m2 < (int)N; m2 += 1024){
        u64 k0 = pk0[m2], k1 = pk1[m2];
        u64 kk = (k0 > k1) ? k0 : k1;          // max f; tie -> smaller j (~bj)
        u32 opt = (~(u32)kk) + 1u;
        atomicAdd(&hbins[opt], 1u);            // LDS atomic
        double smv = (double)sn[m2];
        S1 += smv;
        S2 += smv * (double)opt;
      }
      __syncthreads();
      u32 carry=0u;
      int nch = ((int)P + 1023)/1024;
      for (int ch=0; ch<nch; ++ch){
        int x = ch*1024 + tid;
        u32 v = (x < (int)P) ? hbins[x+1] : 0u;
        u32 incl = blk_scan_incl_u32(v, tid, ws);
        u32 cum = incl + carry;
        if (x < (int)P){
          u32 r = 1u + cum;
          float spv = sp[x];
          sumD   += (double)Dsh[x + r];
          sumSpr += (double)spv * (double)r;
          sumSp  += (double)spv;
        }
        carry += ws[15];                       // chunk total
        __syncthreads();
      }
    } else {
      // generic exact fallback (never at B=16384)
      for (int m2 = tid; m2 < (int)N; m2 += 1024){
        u64 k0 = pk0[m2], k1 = pk1[m2];
        u64 kk = (k0 > k1) ? k0 : k1;
        u32 opt = (~(u32)kk) + 1u;
        double smv = (double)sn[m2];
        S1 += smv; S2 += smv * (double)opt;
      }
      for (int x = tid; x < (int)P; x += 1024){
        u32 target = (u32)x + 1u, cnt2 = 0u;
        for (u32 m2 = 0; m2 < N; ++m2){
          u64 k0 = pk0[m2], k1 = pk1[m2];
          u64 kk = (k0 > k1) ? k0 : k1;
          u32 opt = (~(u32)kk) + 1u;
          cnt2 += (opt <= target) ? 1u : 0u;
        }
        u32 r = 1u + cnt2;
        float spv = sp[x];
        sumD   += (double)Dsh[x + r];
        sumSpr += (double)spv * (double)r;
        sumSp  += (double)spv;
      }
    }
    double totD   = blk_reduce_d(sumD,   tid, ds);
    double totSpr = blk_reduce_d(sumSpr, tid, ds);
    double totSp  = blk_reduce_d(sumSp,  tid, ds);
    double S1t    = blk_reduce_d(S1,     tid, ds);
    double S2t    = blk_reduce_d(S2,     tid, ds);
    if (tid==0){
      double Cc = Cconst[c];
      double Delta = 1.0 - totD/Cc;
      double Fp    = (double)(N+2u)*totSp - 2.0*totSpr;   // sum s_plus*c_plus
      double Fm    = (double)(P+2u)*S1t  - 2.0*S2t;       // sum s_minus*c_minus
      double Fstar = (double)N*totSp - (double)P*S1t;
      myLoss = Delta + (Fp + Fm - Fstar)/((double)P*(double)N);
    }
  }
  if (tid==0){
    atomicExch(&classLoss[c], (u64)__double_as_longlong(myLoss));
    __threadfence();
    u32 old = atomicAdd(doneCount, 1u);
    if (old == (u32)gridDim.x - 1u){
      __threadfence();
      double s=0.0;
      for (int cc=0; cc<NC; ++cc){
        u64 bits = atomicAdd(&classLoss[cc], 0ull);  // coherent read
        s += __longlong_as_double((long long)bits);
      }
      out[0] = (float)(s/(double)NC);
    }
  }
}

extern "C" void kernel_launch(void* const* d_in, const int* in_sizes, int n_in,
                              void* d_out, int out_size, void* d_ws, size_t ws_size,
                              hipStream_t stream) {
  const float* scores = (const float*)d_in[0];
  const int*   labels = (const int*)d_in[1];
  int B  = in_sizes[1];
  int NC = in_sizes[0] / in_sizes[1];
  float* out = (float*)d_out;

  int SD = B + 8;            // per-copy stride of shifted D tables
  int strideAB = B + 8;      // per-class stride of A/B
  int nblkM = (B + 255)/256; // k_main blocks per (class, half)

  char* ws = (char*)d_ws;
  size_t off = 0;
  auto alloc = [&](size_t bytes)->char* {
    char* p = ws + off;
    off = (off + bytes + 255) & ~(size_t)255;
    return p;
  };
  float* Dsh = (float*)alloc((size_t)4*SD*4);
  // ---- zeroed region (must stay contiguous) ----
  char* zbeg = ws + off;
  u32* bhist     = (u32*)alloc((size_t)NC*2*NBUCKET*4);
  u32* doneCount = (u32*)alloc(4);
  char* zend = ws + off;
  // ----------------------------------------------
  u32* Pcnt      = (u32*)alloc((size_t)NC*4);       // written by k_scan
  u32* bstart    = (u32*)alloc((size_t)NC*2*(NBUCKET+1)*4);
  u32* bcursor   = (u32*)alloc((size_t)NC*2*NBUCKET*4);
  u64* keyArr    = (u64*)alloc((size_t)NC*2*B*8);
  float* sPos    = (float*)alloc((size_t)NC*B*4);
  float* sNeg    = (float*)alloc((size_t)NC*B*4);
  float* Aarr    = (float*)alloc((size_t)NC*strideAB*4);
  float* Barr    = (float*)alloc((size_t)NC*strideAB*4);
  double* Cconst = (double*)alloc((size_t)NC*8);
  u64* partKey   = (u64*)alloc((size_t)NC*2*B*8);
  u64* classLoss = (u64*)alloc((size_t)NC*8);

  hipMemsetAsync(zbeg, 0, (size_t)(zend - zbeg), stream);

  k_hist<<<(B*NC+255)/256, 256, 0, stream>>>(scores, labels, B, NC, bhist, Dsh, SD);
  k_scan<<<NC*2, 1024, 0, stream>>>(bhist, bstart, bcursor, Pcnt);
  k_scatter<<<(B*NC+255)/256, 256, 0, stream>>>(scores, labels, B, NC, bcursor, keyArr);
  k_rank<<<dim3((B+255)/256, NC*2), 256, 0, stream>>>(keyArr, bstart, Pcnt, B, sPos, sNeg);
  k_pre<<<NC, 1024, 0, stream>>>(sPos, Pcnt, Dsh, B, strideAB, Aarr, Barr, Cconst);
  k_main<<<dim3(nblkM, NC*2), 256, 0, stream>>>(sNeg, Pcnt, Dsh, SD, Aarr, Barr,
                                                B, strideAB, partKey);
  k_finish<<<NC, 1024, 0, stream>>>(sPos, sNeg, Pcnt, partKey, Dsh, Cconst, B, NC,
                                    classLoss, doneCount, out);
}